// Round 4
// baseline (325.609 us; speedup 1.0000x reference)
//
#include <hip/hip_runtime.h>

#define IMG_H 480
#define IMG_W 640
#define OUT_H 470    // 480 - 10
#define OUT_W 630    // 640 - 10
#define NBATCH 32
#define SW 54        // output columns per 64-lane wave (64 input cols - 10 halo)
#define NSTRIPE 12   // ceil(630 / 54)
#define RCH 30       // output rows per wave-chunk
#define NCHUNK 16    // 16 * 30 = 480 >= 470
#define NROWS (RCH + 10)   // 40 input rows per chunk

#define SSIM_C1 1.0f // (0.01*100)^2
#define SSIM_C2 9.0f // (0.03*100)^2

// Zero-instruction compiler fence: blocks memory-op reordering across it.
// Needed because per-thread alias analysis would otherwise hoist ds_reads of
// other lanes' data above this lane's ds_write (wave-private LDS idiom).
#define LDS_FENCE() asm volatile("" ::: "memory")

// Normalized 11-tap Gaussian (sigma=1.5), matches numpy fp32 window to ~1e-7 rel.
__device__ constexpr float WG[11] = {
    0.00102838f, 0.00759876f, 0.03600077f, 0.10936068f, 0.21300554f,
    0.26601173f,
    0.21300554f, 0.10936068f, 0.03600077f, 0.00759876f, 0.00102838f
};

// One phase of the 11-deep vertical ring with register prefetch of row it+1.
// P must be compile-time so acc[] indices and weight selects fold to literals.
// Requires it ≡ P (mod 11).
#define PHASE(P, IT)                                                          \
  {                                                                           \
    const int it = (IT);                                                      \
    /* prefetch next input row into registers (hides VMEM latency) */         \
    float n1 = 0.f, n2 = 0.f, nb1 = 0.f, nb2 = 0.f;                           \
    if (it + 1 < NROWS) {                                                     \
      int gy = y0 + it + 1; if (gy > IMG_H - 1) gy = IMG_H - 1;               \
      const float* __restrict__ r1 = p1 + gy * IMG_W;                         \
      const float* __restrict__ r2 = p2 + gy * IMG_W;                         \
      n1 = r1[colA]; n2 = r2[colA];                                           \
      if (lane < 10) { nb1 = r1[colB]; nb2 = r2[colB]; }                      \
    }                                                                         \
    /* publish current row to this wave's private LDS row; wave-wide DS   */  \
    /* ops execute in program order, fences stop compiler reordering      */  \
    s1[lane] = c1; s2[lane] = c2;                                             \
    if (lane < 10) { s1[64 + lane] = cb1; s2[64 + lane] = cb2; }              \
    LDS_FENCE();                                                              \
    /* horizontal 11-tap pass, 5 channels, in registers */                    \
    float h1 = 0.f, h2 = 0.f, h11 = 0.f, h22 = 0.f, h12 = 0.f;                \
    _Pragma("unroll")                                                         \
    for (int j = 0; j < 11; ++j) {                                            \
      float v1 = s1[lane + j], v2 = s2[lane + j];                             \
      float t1 = WG[j] * v1, t2 = WG[j] * v2;                                 \
      h1 += t1; h2 += t2;                                                     \
      h11 = fmaf(t1, v1, h11);                                                \
      h22 = fmaf(t2, v2, h22);                                                \
      h12 = fmaf(t1, v2, h12);                                                \
    }                                                                         \
    LDS_FENCE();                                                              \
    /* vertical ring update: slot sl holds output row with y%11==sl */        \
    _Pragma("unroll")                                                         \
    for (int sl = 0; sl < 11; ++sl) {                                         \
      const float wt = WG[((P) - sl + 11) % 11];                              \
      acc[sl][0] = fmaf(wt, h1,  acc[sl][0]);                                 \
      acc[sl][1] = fmaf(wt, h2,  acc[sl][1]);                                 \
      acc[sl][2] = fmaf(wt, h11, acc[sl][2]);                                 \
      acc[sl][3] = fmaf(wt, h22, acc[sl][3]);                                 \
      acc[sl][4] = fmaf(wt, h12, acc[sl][4]);                                 \
    }                                                                         \
    /* slot sc just received its w[10] tap -> output row y completes */       \
    const int sc = ((P) + 1) % 11;                                            \
    const int y = it - 10;                                                    \
    if (it >= 10 && (y0 + y) < OUT_H && valid_col) {                          \
      float m1 = acc[sc][0], m2 = acc[sc][1];                                 \
      float mu1s = m1 * m1, mu2s = m2 * m2, mu12 = m1 * m2;                   \
      float vA = 2.f * (acc[sc][4] - mu12) + SSIM_C2;                         \
      float vB = (acc[sc][2] - mu1s) + (acc[sc][3] - mu2s) + SSIM_C2;         \
      float num = (2.f * mu12 + SSIM_C1) * vA;                                \
      float den = (mu1s + mu2s + SSIM_C1) * vB;                               \
      lsum = fmaf(num, __builtin_amdgcn_rcpf(den), lsum);                     \
    }                                                                         \
    acc[sc][0] = 0.f; acc[sc][1] = 0.f; acc[sc][2] = 0.f;                     \
    acc[sc][3] = 0.f; acc[sc][4] = 0.f;                                       \
    c1 = n1; c2 = n2; cb1 = nb1; cb2 = nb2;                                   \
  }

__global__ __launch_bounds__(256, 6) void ssim_main(
    const float* __restrict__ img1,
    const float* __restrict__ img2,
    float* __restrict__ partials)
{
    const int tid  = threadIdx.x;
    const int lane = tid & 63;
    const int wid  = tid >> 6;          // 4 independent waves per block
    const int stripe = blockIdx.x;
    const int cg     = blockIdx.y;      // chunk group of 4
    const int b      = blockIdx.z;
    const int cy = cg * 4 + wid;
    const int x0 = SW * stripe;
    const int y0 = RCH * cy;

    // per-wave private LDS rows (80-float stride keeps things simple/aligned)
    __shared__ float sh[4][2][80];
    float* __restrict__ s1 = sh[wid][0];
    float* __restrict__ s2 = sh[wid][1];

    const float* __restrict__ p1 = img1 + (size_t)b * (IMG_H * IMG_W);
    const float* __restrict__ p2 = img2 + (size_t)b * (IMG_H * IMG_W);

    int colA = x0 + lane;        if (colA > IMG_W - 1) colA = IMG_W - 1;
    int colB = x0 + 64 + lane;   if (colB > IMG_W - 1) colB = IMG_W - 1;

    const bool valid_col = (lane < SW) && (x0 + lane < OUT_W);

    float acc[11][5];
#pragma unroll
    for (int i = 0; i < 11; ++i)
#pragma unroll
        for (int j = 0; j < 5; ++j) acc[i][j] = 0.f;

    float lsum = 0.f;

    // load row 0 into registers
    float c1, c2, cb1 = 0.f, cb2 = 0.f;
    {
        const float* __restrict__ r1 = p1 + y0 * IMG_W;
        const float* __restrict__ r2 = p2 + y0 * IMG_W;
        c1 = r1[colA]; c2 = r2[colA];
        if (lane < 10) { cb1 = r1[colB]; cb2 = r2[colB]; }
    }

    // 40 input rows: 3 full 11-phase blocks + 7 tail phases (33 % 11 == 0)
    for (int blk = 0; blk < 3; ++blk) {
        const int base = blk * 11;
#pragma unroll
        for (int p = 0; p < 11; ++p) PHASE(p, base + p)
    }
    {
        const int base = 33;
#pragma unroll
        for (int p = 0; p < 7; ++p) PHASE(p, base + p)
    }

    // wave-level reduction (64 lanes)
#pragma unroll
    for (int off = 32; off > 0; off >>= 1)
        lsum += __shfl_down(lsum, off);
    if (lane == 0)
        partials[(b * NCHUNK + cy) * NSTRIPE + stripe] = lsum;
}

__global__ __launch_bounds__(256) void ssim_reduce(
    const float* __restrict__ partials, float* __restrict__ out)
{
    const int n = NSTRIPE * NCHUNK * NBATCH;  // 6144
    __shared__ double red[256];
    int tid = threadIdx.x;
    double s = 0.0;
    for (int i = tid; i < n; i += 256) s += (double)partials[i];
    red[tid] = s;
    __syncthreads();
    for (int k = 128; k > 0; k >>= 1) {
        if (tid < k) red[tid] += red[tid + k];
        __syncthreads();
    }
    if (tid == 0) {
        double mean = red[0] / (double)((size_t)NBATCH * OUT_H * OUT_W);
        out[0] = (float)((1.0 - mean) * 0.5);
    }
}

extern "C" void kernel_launch(void* const* d_in, const int* in_sizes, int n_in,
                              void* d_out, int out_size, void* d_ws, size_t ws_size,
                              hipStream_t stream)
{
    const float* img1 = (const float*)d_in[0];
    const float* img2 = (const float*)d_in[1];
    float* out = (float*)d_out;
    float* partials = (float*)d_ws;  // 6144 floats = 24.6 KB

    dim3 grid(NSTRIPE, NCHUNK / 4, NBATCH);  // 12 x 4 x 32 = 1536 blocks, 4 waves each
    ssim_main<<<grid, dim3(256), 0, stream>>>(img1, img2, partials);
    ssim_reduce<<<1, dim3(256), 0, stream>>>(partials, out);
}

// Round 5
// 291.702 us; speedup vs baseline: 1.1162x; 1.1162x over previous
//
#include <hip/hip_runtime.h>

#define IMG_H 480
#define IMG_W 640
#define OUT_H 470    // 480 - 10
#define OUT_W 630    // 640 - 10
#define NBATCH 32
#define SW 54        // output columns per 64-lane wave (input cols lane..lane+10 all in-wave)
#define NSTRIPE 12   // ceil(630 / 54)
#define RCH 30       // output rows per wave-chunk
#define NCHUNK 16    // 16 * 30 = 480 >= 470
#define NROWS (RCH + 10)   // 40 input rows per chunk

#define SSIM_C1 1.0f // (0.01*100)^2
#define SSIM_C2 9.0f // (0.03*100)^2

// Normalized 11-tap Gaussian (sigma=1.5), matches numpy fp32 window to ~1e-7 rel.
__device__ constexpr float WG[11] = {
    0.00102838f, 0.00759876f, 0.03600077f, 0.10936068f, 0.21300554f,
    0.26601173f,
    0.21300554f, 0.10936068f, 0.03600077f, 0.00759876f, 0.00102838f
};

// lane+j neighbor fetch via ds_bpermute (register crossbar, no LDS storage,
// no barriers, no aliasing). baddr = lane<<2; constant 4*j folds into the
// DS offset field. Wrap for lane+j>63 returns in-wave data (finite), and
// those lanes are masked by valid_col anyway.
__device__ __forceinline__ float lane_shift(int baddr, int j, float v) {
    return __int_as_float(
        __builtin_amdgcn_ds_bpermute(baddr + (j << 2), __float_as_int(v)));
}

// One phase of the 11-deep vertical ring with register prefetch of row it+1.
// P must be compile-time so acc[] indices and weight selects fold; it ≡ P (mod 11).
#define PHASE(P, IT)                                                          \
  {                                                                           \
    const int it = (IT);                                                      \
    /* prefetch next input row into registers (hides VMEM latency) */         \
    float n1 = 0.f, n2 = 0.f;                                                 \
    if (it + 1 < NROWS) {                                                     \
      int gy = y0 + it + 1; if (gy > IMG_H - 1) gy = IMG_H - 1;               \
      const float* __restrict__ r1 = p1 + gy * IMG_W;                         \
      const float* __restrict__ r2 = p2 + gy * IMG_W;                         \
      n1 = r1[colA]; n2 = r2[colA];                                           \
    }                                                                         \
    /* horizontal 11-tap pass via wave crossbar, 5 channels, in registers */  \
    float h1 = 0.f, h2 = 0.f, h11 = 0.f, h22 = 0.f, h12 = 0.f;                \
    _Pragma("unroll")                                                         \
    for (int j = 0; j < 11; ++j) {                                            \
      float v1 = (j == 0) ? c1 : lane_shift(baddr, j, c1);                    \
      float v2 = (j == 0) ? c2 : lane_shift(baddr, j, c2);                    \
      float t1 = WG[j] * v1, t2 = WG[j] * v2;                                 \
      h1 += t1; h2 += t2;                                                     \
      h11 = fmaf(t1, v1, h11);                                                \
      h22 = fmaf(t2, v2, h22);                                                \
      h12 = fmaf(t1, v2, h12);                                                \
    }                                                                         \
    /* vertical ring update: slot sl holds output row with y%11==sl */        \
    _Pragma("unroll")                                                         \
    for (int sl = 0; sl < 11; ++sl) {                                         \
      const float wt = WG[((P) - sl + 11) % 11];                              \
      acc[sl][0] = fmaf(wt, h1,  acc[sl][0]);                                 \
      acc[sl][1] = fmaf(wt, h2,  acc[sl][1]);                                 \
      acc[sl][2] = fmaf(wt, h11, acc[sl][2]);                                 \
      acc[sl][3] = fmaf(wt, h22, acc[sl][3]);                                 \
      acc[sl][4] = fmaf(wt, h12, acc[sl][4]);                                 \
    }                                                                         \
    /* slot sc just received its w[10] tap -> output row y completes */       \
    const int sc = ((P) + 1) % 11;                                            \
    const int y = it - 10;                                                    \
    if (it >= 10 && (y0 + y) < OUT_H && valid_col) {                          \
      float m1 = acc[sc][0], m2 = acc[sc][1];                                 \
      float mu1s = m1 * m1, mu2s = m2 * m2, mu12 = m1 * m2;                   \
      float vA = 2.f * (acc[sc][4] - mu12) + SSIM_C2;                         \
      float vB = (acc[sc][2] - mu1s) + (acc[sc][3] - mu2s) + SSIM_C2;         \
      float num = (2.f * mu12 + SSIM_C1) * vA;                                \
      float den = (mu1s + mu2s + SSIM_C1) * vB;                               \
      lsum = fmaf(num, __builtin_amdgcn_rcpf(den), lsum);                     \
    }                                                                         \
    acc[sc][0] = 0.f; acc[sc][1] = 0.f; acc[sc][2] = 0.f;                     \
    acc[sc][3] = 0.f; acc[sc][4] = 0.f;                                       \
    c1 = n1; c2 = n2;                                                         \
  }

__global__ __launch_bounds__(256, 5) void ssim_main(
    const float* __restrict__ img1,
    const float* __restrict__ img2,
    float* __restrict__ partials)
{
    const int tid  = threadIdx.x;
    const int lane = tid & 63;
    const int wid  = tid >> 6;          // 4 independent waves per block (no barriers)
    const int stripe = blockIdx.x;
    const int cg     = blockIdx.y;      // chunk group of 4
    const int b      = blockIdx.z;
    const int cy = cg * 4 + wid;
    const int x0 = SW * stripe;
    const int y0 = RCH * cy;

    const float* __restrict__ p1 = img1 + (size_t)b * (IMG_H * IMG_W);
    const float* __restrict__ p2 = img2 + (size_t)b * (IMG_H * IMG_W);

    int colA = x0 + lane;  if (colA > IMG_W - 1) colA = IMG_W - 1;
    const int baddr = lane << 2;

    const bool valid_col = (lane < SW) && (x0 + lane < OUT_W);

    float acc[11][5];
#pragma unroll
    for (int i = 0; i < 11; ++i)
#pragma unroll
        for (int j = 0; j < 5; ++j) acc[i][j] = 0.f;

    float lsum = 0.f;

    // load row 0 into registers
    float c1, c2;
    {
        const float* __restrict__ r1 = p1 + y0 * IMG_W;
        const float* __restrict__ r2 = p2 + y0 * IMG_W;
        c1 = r1[colA]; c2 = r2[colA];
    }

    // 40 input rows: 3 full 11-phase blocks + 7 tail phases
    for (int blk = 0; blk < 3; ++blk) {
        const int base = blk * 11;
#pragma unroll
        for (int p = 0; p < 11; ++p) PHASE(p, base + p)
    }
    {
        const int base = 33;
#pragma unroll
        for (int p = 0; p < 7; ++p) PHASE(p, base + p)
    }

    // wave-level reduction (64 lanes); lanes >= SW carry lsum == 0
#pragma unroll
    for (int off = 32; off > 0; off >>= 1)
        lsum += __shfl_down(lsum, off);
    if (lane == 0)
        partials[(b * NCHUNK + cy) * NSTRIPE + stripe] = lsum;
}

__global__ __launch_bounds__(256) void ssim_reduce(
    const float* __restrict__ partials, float* __restrict__ out)
{
    const int n = NSTRIPE * NCHUNK * NBATCH;  // 6144
    __shared__ double red[256];
    int tid = threadIdx.x;
    double s = 0.0;
    for (int i = tid; i < n; i += 256) s += (double)partials[i];
    red[tid] = s;
    __syncthreads();
    for (int k = 128; k > 0; k >>= 1) {
        if (tid < k) red[tid] += red[tid + k];
        __syncthreads();
    }
    if (tid == 0) {
        double mean = red[0] / (double)((size_t)NBATCH * OUT_H * OUT_W);
        out[0] = (float)((1.0 - mean) * 0.5);
    }
}

extern "C" void kernel_launch(void* const* d_in, const int* in_sizes, int n_in,
                              void* d_out, int out_size, void* d_ws, size_t ws_size,
                              hipStream_t stream)
{
    const float* img1 = (const float*)d_in[0];
    const float* img2 = (const float*)d_in[1];
    float* out = (float*)d_out;
    float* partials = (float*)d_ws;  // 6144 floats = 24.6 KB

    dim3 grid(NSTRIPE, NCHUNK / 4, NBATCH);  // 12 x 4 x 32 = 1536 blocks, 4 waves each
    ssim_main<<<grid, dim3(256), 0, stream>>>(img1, img2, partials);
    ssim_reduce<<<1, dim3(256), 0, stream>>>(partials, out);
}

// Round 6
// 151.427 us; speedup vs baseline: 2.1503x; 1.9264x over previous
//
#include <hip/hip_runtime.h>

#define IMG_H 480
#define IMG_W 640
#define OUT_H 470    // 480 - 10
#define OUT_W 630    // 640 - 10
#define NBATCH 32
#define SW 54        // output columns per 64-lane wave (input cols lane..lane+10 all in-wave)
#define NSTRIPE 12   // ceil(630 / 54)
#define RCH 30       // output rows per wave-chunk
#define NCHUNK 16    // 16 * 30 = 480 >= 470
#define NROWS (RCH + 10)   // 40 input rows per chunk

#define SSIM_C1 1.0f // (0.01*100)^2
#define SSIM_C2 9.0f // (0.03*100)^2

// Normalized 11-tap Gaussian (sigma=1.5), matches numpy fp32 window to ~1e-7 rel.
__device__ constexpr float WG[11] = {
    0.00102838f, 0.00759876f, 0.03600077f, 0.10936068f, 0.21300554f,
    0.26601173f,
    0.21300554f, 0.10936068f, 0.03600077f, 0.00759876f, 0.00102838f
};

// lane+j neighbor fetch via ds_bpermute (register crossbar, no LDS storage,
// no barriers, no aliasing). baddr = lane<<2; constant 4*j folds into the
// DS offset field. Wrap for lane+j>63 returns in-wave data (finite), and
// those lanes are masked by valid_col anyway.
__device__ __forceinline__ float lane_shift(int baddr, int j, float v) {
    return __int_as_float(
        __builtin_amdgcn_ds_bpermute(baddr + (j << 2), __float_as_int(v)));
}

// One phase of the 11-deep vertical ring with register prefetch of row it+1.
// P must be compile-time so acc[] indices and weight selects fold; it ≡ P (mod 11).
// NOTE: the 55-reg ring + ~45 working regs needs a >=128 reg/wave budget.
// gfx950 has a UNIFIED VGPR/AGPR pool (~512/wave): launch_bounds waves/EU > 4
// caps the budget below the live set and spills the ring to scratch
// (R4/R5 regression: WRITE_SIZE 86-229 MB of spill traffic). Keep (64,4).
#define PHASE(P, IT)                                                          \
  {                                                                           \
    const int it = (IT);                                                      \
    /* prefetch next input row into registers (hides VMEM latency) */         \
    float n1 = 0.f, n2 = 0.f;                                                 \
    if (it + 1 < NROWS) {                                                     \
      int gy = y0 + it + 1; if (gy > IMG_H - 1) gy = IMG_H - 1;               \
      const float* __restrict__ r1 = p1 + gy * IMG_W;                         \
      const float* __restrict__ r2 = p2 + gy * IMG_W;                         \
      n1 = r1[colA]; n2 = r2[colA];                                           \
    }                                                                         \
    /* horizontal 11-tap pass via wave crossbar, 5 channels, in registers */  \
    float h1 = 0.f, h2 = 0.f, h11 = 0.f, h22 = 0.f, h12 = 0.f;                \
    _Pragma("unroll")                                                         \
    for (int j = 0; j < 11; ++j) {                                            \
      float v1 = (j == 0) ? c1 : lane_shift(baddr, j, c1);                    \
      float v2 = (j == 0) ? c2 : lane_shift(baddr, j, c2);                    \
      float t1 = WG[j] * v1, t2 = WG[j] * v2;                                 \
      h1 += t1; h2 += t2;                                                     \
      h11 = fmaf(t1, v1, h11);                                                \
      h22 = fmaf(t2, v2, h22);                                                \
      h12 = fmaf(t1, v2, h12);                                                \
    }                                                                         \
    /* vertical ring update: slot sl holds output row with y%11==sl */        \
    _Pragma("unroll")                                                         \
    for (int sl = 0; sl < 11; ++sl) {                                         \
      const float wt = WG[((P) - sl + 11) % 11];                              \
      acc[sl][0] = fmaf(wt, h1,  acc[sl][0]);                                 \
      acc[sl][1] = fmaf(wt, h2,  acc[sl][1]);                                 \
      acc[sl][2] = fmaf(wt, h11, acc[sl][2]);                                 \
      acc[sl][3] = fmaf(wt, h22, acc[sl][3]);                                 \
      acc[sl][4] = fmaf(wt, h12, acc[sl][4]);                                 \
    }                                                                         \
    /* slot sc just received its w[10] tap -> output row y completes */       \
    const int sc = ((P) + 1) % 11;                                            \
    const int y = it - 10;                                                    \
    if (it >= 10 && (y0 + y) < OUT_H && valid_col) {                          \
      float m1 = acc[sc][0], m2 = acc[sc][1];                                 \
      float mu1s = m1 * m1, mu2s = m2 * m2, mu12 = m1 * m2;                   \
      float vA = 2.f * (acc[sc][4] - mu12) + SSIM_C2;                         \
      float vB = (acc[sc][2] - mu1s) + (acc[sc][3] - mu2s) + SSIM_C2;         \
      float num = (2.f * mu12 + SSIM_C1) * vA;                                \
      float den = (mu1s + mu2s + SSIM_C1) * vB;                               \
      lsum = fmaf(num, __builtin_amdgcn_rcpf(den), lsum);                     \
    }                                                                         \
    acc[sc][0] = 0.f; acc[sc][1] = 0.f; acc[sc][2] = 0.f;                     \
    acc[sc][3] = 0.f; acc[sc][4] = 0.f;                                       \
    c1 = n1; c2 = n2;                                                         \
  }

__global__ __launch_bounds__(64, 4) void ssim_main(
    const float* __restrict__ img1,
    const float* __restrict__ img2,
    float* __restrict__ partials)
{
    const int lane   = threadIdx.x;
    const int stripe = blockIdx.x;
    const int cy     = blockIdx.y;
    const int b      = blockIdx.z;
    const int x0 = SW * stripe;
    const int y0 = RCH * cy;

    const float* __restrict__ p1 = img1 + (size_t)b * (IMG_H * IMG_W);
    const float* __restrict__ p2 = img2 + (size_t)b * (IMG_H * IMG_W);

    int colA = x0 + lane;  if (colA > IMG_W - 1) colA = IMG_W - 1;
    const int baddr = lane << 2;

    const bool valid_col = (lane < SW) && (x0 + lane < OUT_W);

    float acc[11][5];
#pragma unroll
    for (int i = 0; i < 11; ++i)
#pragma unroll
        for (int j = 0; j < 5; ++j) acc[i][j] = 0.f;

    float lsum = 0.f;

    // load row 0 into registers
    float c1, c2;
    {
        const float* __restrict__ r1 = p1 + y0 * IMG_W;
        const float* __restrict__ r2 = p2 + y0 * IMG_W;
        c1 = r1[colA]; c2 = r2[colA];
    }

    // 40 input rows: 3 full 11-phase blocks + 7 tail phases
    for (int blk = 0; blk < 3; ++blk) {
        const int base = blk * 11;
#pragma unroll
        for (int p = 0; p < 11; ++p) PHASE(p, base + p)
    }
    {
        const int base = 33;
#pragma unroll
        for (int p = 0; p < 7; ++p) PHASE(p, base + p)
    }

    // wave-level reduction (64 lanes); lanes >= SW carry lsum == 0
#pragma unroll
    for (int off = 32; off > 0; off >>= 1)
        lsum += __shfl_down(lsum, off);
    if (lane == 0)
        partials[(b * NCHUNK + cy) * NSTRIPE + stripe] = lsum;
}

__global__ __launch_bounds__(256) void ssim_reduce(
    const float* __restrict__ partials, float* __restrict__ out)
{
    const int n = NSTRIPE * NCHUNK * NBATCH;  // 6144
    __shared__ double red[256];
    int tid = threadIdx.x;
    double s = 0.0;
    for (int i = tid; i < n; i += 256) s += (double)partials[i];
    red[tid] = s;
    __syncthreads();
    for (int k = 128; k > 0; k >>= 1) {
        if (tid < k) red[tid] += red[tid + k];
        __syncthreads();
    }
    if (tid == 0) {
        double mean = red[0] / (double)((size_t)NBATCH * OUT_H * OUT_W);
        out[0] = (float)((1.0 - mean) * 0.5);
    }
}

extern "C" void kernel_launch(void* const* d_in, const int* in_sizes, int n_in,
                              void* d_out, int out_size, void* d_ws, size_t ws_size,
                              hipStream_t stream)
{
    const float* img1 = (const float*)d_in[0];
    const float* img2 = (const float*)d_in[1];
    float* out = (float*)d_out;
    float* partials = (float*)d_ws;  // 6144 floats = 24.6 KB

    dim3 grid(NSTRIPE, NCHUNK, NBATCH);  // 12 x 16 x 32 = 6144 single-wave blocks
    ssim_main<<<grid, dim3(64), 0, stream>>>(img1, img2, partials);
    ssim_reduce<<<1, dim3(256), 0, stream>>>(partials, out);
}